// Round 1
// baseline (189.780 us; speedup 1.0000x reference)
//
#include <hip/hip_runtime.h>

#define N_Q   16384
#define C_DIM 128
#define S_CAM 6
#define M_VAL 1400   // 28*50
#define D_Z   8
#define HF    28
#define WF    50
#define QPB   8      // queries per block; 32 lanes/query = (pt-half, cam-half, 8x16ch)

typedef float f32x2 __attribute__((ext_vector_type(2)));

__device__ __forceinline__ bool mask_any(const unsigned char* __restrict__ mask,
                                         int mflag, size_t mbase){
  if(mflag==0){
    int any=0;
    #pragma unroll
    for(int d=0;d<D_Z;d++) any |= mask[mbase+d];
    return any!=0;
  } else if(mflag==1){
    const int* mp = (const int*)mask;  int any=0;
    #pragma unroll
    for(int d=0;d<D_Z;d++) any |= mp[mbase+d];
    return any!=0;
  } else {
    const long long* mp = (const long long*)mask;  long long any=0;
    #pragma unroll
    for(int d=0;d<D_Z;d++) any |= mp[mbase+d];
    return any!=0;
  }
}

// fp8x16 corner accumulate as f32x2 pairs -> v_pk_fma_f32 (8 pk-FMA vs 16 FMA).
__device__ __forceinline__ void corner_acc(const uint4 cv, const float wgt,
                                           f32x2* __restrict__ acc2){
  const f32x2 w2 = {wgt, wgt};
  const unsigned dw[4] = {cv.x, cv.y, cv.z, cv.w};
  #pragma unroll
  for(int j=0;j<4;j++){
    acc2[j*2+0] += w2 * __builtin_amdgcn_cvt_pk_f32_fp8(dw[j], false);
    acc2[j*2+1] += w2 * __builtin_amdgcn_cvt_pk_f32_fp8(dw[j], true);
  }
}

// ---------------------------------------------------------------------------
// v = value @ Wv + bv (8400x128 @ 128x128) -> FP8 e4m3 workspace (HW cvt;
// same HW format encode+decode -> self-consistent roundtrip). Halves gather
// bytes AND lane-requests vs fp16.
// Block 0 piggybacks the bev_mask upload-format sniff (0=u8,1=i32,2=i64).
// ---------------------------------------------------------------------------
__global__ __launch_bounds__(256)
void value_proj_kernel(const float* __restrict__ value,
                       const float* __restrict__ Wv,
                       const float* __restrict__ bv,
                       unsigned char* __restrict__ v8,
                       const unsigned char* __restrict__ mask,
                       int* __restrict__ flag){
  __shared__ float tile[8][C_DIM];
  __shared__ int s_cntA, s_cntB;
  const int tid = threadIdx.x;
  const int col = tid & 127;
  const int rh  = tid >> 7;                    // rows rh*4 .. rh*4+3
  const int r0  = blockIdx.x * 8;
  if(blockIdx.x==0 && tid==0){ s_cntA=0; s_cntB=0; }
  {
    const float4* src = (const float4*)(value + (size_t)r0*C_DIM);
    ((float4*)&tile[0][0])[tid] = src[tid];
  }
  __syncthreads();
  float acc[4];
  const float bias = bv[col];
  #pragma unroll
  for(int r=0;r<4;r++) acc[r]=bias;
  for(int k=0;k<C_DIM;k+=4){
    const float w0 = Wv[(k+0)*C_DIM + col];
    const float w1 = Wv[(k+1)*C_DIM + col];
    const float w2 = Wv[(k+2)*C_DIM + col];
    const float w3 = Wv[(k+3)*C_DIM + col];
    #pragma unroll
    for(int r=0;r<4;r++){
      const float4 t = *(const float4*)&tile[rh*4+r][k];
      acc[r] += t.x*w0 + t.y*w1 + t.z*w2 + t.w*w3;
    }
  }
  #pragma unroll
  for(int r=0;r<4;r++){
    const int pk = __builtin_amdgcn_cvt_pk_fp8_f32(acc[r], acc[r], 0, false);
    v8[(size_t)(r0+rh*4+r)*C_DIM + col] = (unsigned char)(pk & 0xff);
  }
  if(blockIdx.x==0){
    int a=0, b=0;
    for(int i=tid;i<1024;i+=256){
      const unsigned char v = mask[i];
      if(((i&3)!=0) && v) a=1;
      if(((i&7)==4) && v) b=1;
    }
    if(a) atomicOr(&s_cntA,1);
    if(b) atomicOr(&s_cntB,1);
    __syncthreads();
    if(tid==0) flag[0] = s_cntA ? 0 : (s_cntB ? 1 : 2);
  }
}

// ---------------------------------------------------------------------------
// Fused deformable attention. 32 lanes/query: lane = (pg pt-half, sg cam-half,
// ll 16-ch group). vs previous 16-lane layout: per-lane gather work halves
// (latency chain halves) and grid doubles (2048 blocks -> 8 blocks/CU, ~28
// waves/CU resident vs 16) -- attacks the measured latency-bound regime
// (VALUBusy 26%, HBM 3%, occupancy 27%). The 4 (pg,sg) partials live in the
// SAME wave (l^8, l^16) -> merged by two __shfl_xor butterflies, dropping the
// LDS RMW merge and its 2 barriers. FP8 decode via v_cvt_pk_f32_fp8 feeding
// packed v_pk_fma_f32 accumulate.
// ---------------------------------------------------------------------------
__global__ __launch_bounds__(256)
void fused_deform_kernel(const unsigned char* __restrict__ v8,
                         const float* __restrict__ query,
                         const float* __restrict__ query_pos,
                         const float* __restrict__ Wo, const float* __restrict__ bo,
                         const float* __restrict__ Wa, const float* __restrict__ ba,
                         const float* __restrict__ ref,
                         const unsigned char* __restrict__ mask,
                         const int* __restrict__ flag,
                         const float* __restrict__ Wout,
                         const float* __restrict__ bout,
                         float* __restrict__ out){
  __shared__ float  qs[QPB][C_DIM+4];        // q staging; reused as slot sums
  __shared__ float  offs[QPB][68];           // 68 mod 32 = 4
  __shared__ float  attns[QPB][36];
  __shared__ float  logits[QPB][36];
  __shared__ float2 refs[QPB][S_CAM*D_Z+1];  // 49 f2 rows
  __shared__ int    activ[QPB][S_CAM];
  __shared__ float  cinv[QPB];

  const int tid = threadIdx.x;
  const int n0  = blockIdx.x * QPB;
  const int mflag = flag[0];
  const int qi = tid >> 5;                   // query in block (0..7)
  const int l  = tid & 31;                   // lane within query group

  // ---- 0) ref prefetch (QPB*48 = 384 float2; <=2/thread) ----
  float2 rpre0, rpre1;
  {
    const int q0 = tid/48, r0 = tid%48;
    rpre0 = ((const float2*)ref)[((size_t)(r0>>3)*N_Q + (n0+q0))*D_Z + (r0&7)];
    if(tid < 128){
      const int e1 = tid + 256;
      const int q1 = e1/48, r1 = e1%48;
      rpre1 = ((const float2*)ref)[((size_t)(r1>>3)*N_Q + (n0+q1))*D_Z + (r1&7)];
    }
  }

  // ---- 1) q = query + query_pos (8q x 128ch = 256 float4, 1/thread) ----
  {
    const float4* qa = (const float4*)(query     + (size_t)n0*C_DIM);
    const float4* qb = (const float4*)(query_pos + (size_t)n0*C_DIM);
    const int r = tid >> 5, c4 = tid & 31;
    const float4 A = qa[tid], B = qb[tid];
    *(float4*)&qs[r][c4*4] = make_float4(A.x+B.x, A.y+B.y, A.z+B.z, A.w+B.w);
  }
  __syncthreads();

  // ---- 2) projections: lane l -> off cols l*2..l*2+1, logit col l ----
  {
    float ao0 = bo[l*2+0], ao1 = bo[l*2+1];
    float aa  = ba[l];
    for(int k=0;k<C_DIM;k++){
      const float qv = qs[qi][k];
      const float2 wo = *(const float2*)&Wo[k*64 + l*2];
      const float  wa = Wa[k*32 + l];
      ao0 += qv*wo.x; ao1 += qv*wo.y; aa += qv*wa;
    }
    offs[qi][l*2+0] = ao0;  offs[qi][l*2+1] = ao1;
    logits[qi][l] = aa;
  }
  {
    refs[tid/48][tid%48] = rpre0;
    if(tid < 128){
      const int e1 = tid + 256;
      refs[e1/48][e1%48] = rpre1;
    }
  }
  if(tid < QPB*S_CAM){
    const int q2 = tid / S_CAM, s = tid % S_CAM;
    activ[q2][s] = mask_any(mask, mflag, ((size_t)s*N_Q + (n0+q2))*D_Z) ? 1 : 0;
  }
  __syncthreads();
  if(tid < QPB*4){                           // softmax over P=8: (q2, h)
    const int q2 = tid >> 2, h = tid & 3;
    const float* L = &logits[q2][h*8];
    float mx = L[0];
    #pragma unroll
    for(int p=1;p<8;p++) mx = fmaxf(mx, L[p]);
    float e[8], ssum = 0.f;
    #pragma unroll
    for(int p=0;p<8;p++){ e[p] = __expf(L[p]-mx); ssum += e[p]; }
    const float inv = 1.f/ssum;
    #pragma unroll
    for(int p=0;p<8;p++) attns[q2][h*8+p] = e[p]*inv;
  } else if(tid >= 256-QPB){
    const int q2 = tid - (256-QPB);
    int c = 0;
    #pragma unroll
    for(int s=0;s<S_CAM;s++) c += activ[q2][s];
    cinv[q2] = 1.f / fmaxf((float)c, 1.f);
  }
  __syncthreads();

  // ---- 3) barrier-free FP8 gather: 3 cams x 4 points per lane ----
  const int pg  = l >> 4;                    // points pg*4 .. pg*4+3
  const int sg  = (l >> 3) & 1;              // cams sg*3 .. sg*3+2
  const int ll  = l & 7;                     // 16-ch group
  const int gch = ll*16;                     // first channel
  const int gh  = ll >> 1;                   // head (32 ch/head)
  f32x2 acc2[8];
  #pragma unroll
  for(int i=0;i<8;i++) acc2[i] = (f32x2){0.f, 0.f};

  for(int s=sg*3; s<sg*3+3; s++){
    if(!activ[qi][s]) continue;
    const unsigned char* vb = v8 + (size_t)s*M_VAL*C_DIM + gch;
    #pragma unroll 2
    for(int pp=0;pp<4;pp++){                 // point p <-> z-anchor d=p (P//D==1)
      const int p = pg*4 + pp;
      const float2 r2 = refs[qi][s*8+p];
      const float ox = offs[qi][gh*16+p*2+0];
      const float oy = offs[qi][gh*16+p*2+1];
      const float x = fmaf(r2.x, (float)WF, ox - 0.5f);
      const float y = fmaf(r2.y, (float)HF, oy - 0.5f);
      const float x0f = floorf(x), y0f = floorf(y);
      const float fx = x - x0f,    fy = y - y0f;
      const int x0 = (int)x0f, y0 = (int)y0f;
      const int x1 = x0+1,     y1 = y0+1;
      const float at = attns[qi][gh*8+p];
      const float wx0 = (x0>=0 && x0<WF) ? (1.f-fx) : 0.f;
      const float wx1 = (x1>=0 && x1<WF) ? fx       : 0.f;
      const float wy0 = ((y0>=0 && y0<HF) ? (1.f-fy) : 0.f) * at;
      const float wy1 = ((y1>=0 && y1<HF) ? fy       : 0.f) * at;
      const int x0c = min(max(x0,0), WF-1), x1c = min(max(x1,0), WF-1);
      const int y0c = min(max(y0,0), HF-1), y1c = min(max(y1,0), HF-1);
      const float w00 = wx0*wy0, w01 = wx1*wy0, w10 = wx0*wy1, w11 = wx1*wy1;
      const uint4 c00 = *(const uint4*)(vb + (size_t)(y0c*WF+x0c)*C_DIM);
      const uint4 c01 = *(const uint4*)(vb + (size_t)(y0c*WF+x1c)*C_DIM);
      const uint4 c10 = *(const uint4*)(vb + (size_t)(y1c*WF+x0c)*C_DIM);
      const uint4 c11 = *(const uint4*)(vb + (size_t)(y1c*WF+x1c)*C_DIM);
      corner_acc(c00, w00, acc2);
      corner_acc(c01, w01, acc2);
      corner_acc(c10, w10, acc2);
      corner_acc(c11, w11, acc2);
    }
  }

  // ---- 4) merge 4 (pg,sg) partials in-register: same-wave butterflies ----
  float* accf = (float*)acc2;
  #pragma unroll
  for(int i=0;i<16;i++) accf[i] += __shfl_xor(accf[i], 16);  // merge pt halves
  #pragma unroll
  for(int i=0;i<16;i++) accf[i] += __shfl_xor(accf[i], 8);   // merge cam halves
  if(l < 8){                                 // one copy per 16-ch group writes
    const float inv = cinv[qi];
    #pragma unroll
    for(int i=0;i<4;i++)
      *(float4*)&qs[qi][gch+i*4] = make_float4(accf[i*4+0]*inv, accf[i*4+1]*inv,
                                               accf[i*4+2]*inv, accf[i*4+3]*inv);
  }
  // qs row qi is written and read only by query qi's own half-wave; DS ops
  // from one wave complete in order -> no block barrier needed here.

  // ---- 5) out-proj + residual: 4 output cols per lane ----
  {
    const int c0 = l*4;
    const int n  = n0 + qi;
    const float4 bA = *(const float4*)&bout[c0];
    const float4 rA = *(const float4*)&query[(size_t)n*C_DIM + c0];
    float o0=bA.x+rA.x, o1=bA.y+rA.y, o2=bA.z+rA.z, o3=bA.w+rA.w;
    for(int k=0;k<C_DIM;k++){
      const float sv = qs[qi][k];
      const float4 wA = *(const float4*)&Wout[(size_t)k*C_DIM + c0];
      o0 += sv*wA.x; o1 += sv*wA.y; o2 += sv*wA.z; o3 += sv*wA.w;
    }
    *(float4*)&out[(size_t)n*C_DIM + c0] = make_float4(o0,o1,o2,o3);
  }
}

extern "C" void kernel_launch(void* const* d_in, const int* in_sizes, int n_in,
                              void* d_out, int out_size, void* d_ws, size_t ws_size,
                              hipStream_t stream){
  const float* query     = (const float*)d_in[0];
  const float* query_pos = (const float*)d_in[1];
  const float* value     = (const float*)d_in[2];
  const float* ref       = (const float*)d_in[3];
  const unsigned char* mask = (const unsigned char*)d_in[4];
  const float* Wv   = (const float*)d_in[5];
  const float* bv   = (const float*)d_in[6];
  const float* Wo   = (const float*)d_in[7];
  const float* bo   = (const float*)d_in[8];
  const float* Wa   = (const float*)d_in[9];
  const float* ba   = (const float*)d_in[10];
  const float* Wout = (const float*)d_in[11];
  const float* bout = (const float*)d_in[12];
  float* out = (float*)d_out;

  int* flag = (int*)d_ws;
  unsigned char* v8 = (unsigned char*)((char*)d_ws + 64);

  value_proj_kernel<<<(S_CAM*M_VAL)/8, 256, 0, stream>>>(value, Wv, bv, v8, mask, flag);
  fused_deform_kernel<<<N_Q/QPB, 256, 0, stream>>>(v8, query, query_pos,
                                                   Wo, bo, Wa, ba, ref, mask, flag,
                                                   Wout, bout, out);
}

// Round 2
// 165.981 us; speedup vs baseline: 1.1434x; 1.1434x over previous
//
#include <hip/hip_runtime.h>

#define N_Q   16384
#define C_DIM 128
#define S_CAM 6
#define M_VAL 1400   // 28*50
#define D_Z   8
#define HF    28
#define WF    50
#define QPB   8      // queries per block; 32 lanes/query in gather phase

typedef float f32x2 __attribute__((ext_vector_type(2)));

__device__ __forceinline__ bool mask_any(const unsigned char* __restrict__ mask,
                                         int mflag, size_t mbase){
  if(mflag==0){
    int any=0;
    #pragma unroll
    for(int d=0;d<D_Z;d++) any |= mask[mbase+d];
    return any!=0;
  } else if(mflag==1){
    const int* mp = (const int*)mask;  int any=0;
    #pragma unroll
    for(int d=0;d<D_Z;d++) any |= mp[mbase+d];
    return any!=0;
  } else {
    const long long* mp = (const long long*)mask;  long long any=0;
    #pragma unroll
    for(int d=0;d<D_Z;d++) any |= mp[mbase+d];
    return any!=0;
  }
}

// fp8x16 corner accumulate as f32x2 pairs -> v_pk_fma_f32.
__device__ __forceinline__ void corner_acc(const uint4 cv, const float wgt,
                                           f32x2* __restrict__ acc2){
  const f32x2 w2 = {wgt, wgt};
  const unsigned dw[4] = {cv.x, cv.y, cv.z, cv.w};
  #pragma unroll
  for(int j=0;j<4;j++){
    acc2[j*2+0] += w2 * __builtin_amdgcn_cvt_pk_f32_fp8(dw[j], false);
    acc2[j*2+1] += w2 * __builtin_amdgcn_cvt_pk_f32_fp8(dw[j], true);
  }
}

// ---------------------------------------------------------------------------
// v = value @ Wv + bv -> FP8 e4m3 workspace.
// TA-pipe fix: k is split across the two 128-thread halves of the block
// (kh = tid>>7). Each thread loads 4 Wv scalars per 4-k (64 load instrs/wave,
// was 128); halves merged through LDS. Bias added only in kh=0 half.
// Block 0 piggybacks the bev_mask upload-format sniff (0=u8,1=i32,2=i64).
// ---------------------------------------------------------------------------
__global__ __launch_bounds__(256)
void value_proj_kernel(const float* __restrict__ value,
                       const float* __restrict__ Wv,
                       const float* __restrict__ bv,
                       unsigned char* __restrict__ v8,
                       const unsigned char* __restrict__ mask,
                       int* __restrict__ flag){
  __shared__ float tile[8][C_DIM];
  __shared__ float part[8][C_DIM];
  __shared__ int s_cntA, s_cntB;
  const int tid = threadIdx.x;
  const int c   = tid & 127;                 // output column
  const int kh  = tid >> 7;                  // k-half
  const int r0  = blockIdx.x * 8;
  if(blockIdx.x==0 && tid==0){ s_cntA=0; s_cntB=0; }
  {
    const float4* src = (const float4*)(value + (size_t)r0*C_DIM);
    ((float4*)&tile[0][0])[tid] = src[tid];
  }
  __syncthreads();
  float acc[8];
  {
    const float bias = kh ? 0.f : bv[c];     // bias once (kh=0 half only)
    #pragma unroll
    for(int r=0;r<8;r++) acc[r]=bias;
  }
  {
    const float* Wp = Wv + (size_t)kh*64*C_DIM + c;
    const int k00 = kh*64;
    for(int k0=0;k0<64;k0+=4){
      const float w0 = Wp[0];
      const float w1 = Wp[C_DIM];
      const float w2 = Wp[2*C_DIM];
      const float w3 = Wp[3*C_DIM];
      #pragma unroll
      for(int r=0;r<8;r++){
        const float4 t = *(const float4*)&tile[r][k00+k0];
        acc[r] += t.x*w0 + t.y*w1 + t.z*w2 + t.w*w3;
      }
      Wp += 4*C_DIM;
    }
  }
  if(kh){
    #pragma unroll
    for(int r=0;r<8;r++) part[r][c] = acc[r];
  }
  __syncthreads();
  if(!kh){
    #pragma unroll
    for(int r=0;r<8;r++){
      const float v = acc[r] + part[r][c];
      const int pk = __builtin_amdgcn_cvt_pk_fp8_f32(v, v, 0, false);
      v8[(size_t)(r0+r)*C_DIM + c] = (unsigned char)(pk & 0xff);
    }
  }
  if(blockIdx.x==0){
    int a=0, b=0;
    for(int i=tid;i<1024;i+=256){
      const unsigned char v = mask[i];
      if(((i&3)!=0) && v) a=1;
      if(((i&7)==4) && v) b=1;
    }
    if(a) atomicOr(&s_cntA,1);
    if(b) atomicOr(&s_cntB,1);
    __syncthreads();
    if(tid==0) flag[0] = s_cntA ? 0 : (s_cntB ? 1 : 2);
  }
}

// ---------------------------------------------------------------------------
// Fused deformable attention.
// R2 theory: the kernel is bound by the per-CU vector-memory address pipe
// (~4 lane-addr/cy => ~16 cy per 64-lane VMEM instr regardless of cache hit).
// Old per-wave VMEM: ph2 256 + ph5 128 + gather 48 ~= 450 instr ~= 7.2K cy TA
// per wave x 32 waves/CU ~= the whole 240K-cycle wall. Fix: both queries of a
// wave need IDENTICAL weight rows -> split k across the wave's two 32-lane
// halves; each lane loads one float4 of W serving BOTH queries; merge k-halves
// with __shfl_xor(...,32). ph2: Wo||Wa as 96 cols / 24 float4 lanes, 64 iters.
// ph5: 32 float4 col-groups, 64 iters. Per-wave VMEM ~450 -> ~190 instr.
// Bias/residual only initialized in the kh=0 half (merge would double it).
// Gather phase unchanged (16B fp8 loads, shuffle corner-merge, barrier-free).
// ---------------------------------------------------------------------------
__global__ __launch_bounds__(256)
void fused_deform_kernel(const unsigned char* __restrict__ v8,
                         const float* __restrict__ query,
                         const float* __restrict__ query_pos,
                         const float* __restrict__ Wo, const float* __restrict__ bo,
                         const float* __restrict__ Wa, const float* __restrict__ ba,
                         const float* __restrict__ ref,
                         const unsigned char* __restrict__ mask,
                         const int* __restrict__ flag,
                         const float* __restrict__ Wout,
                         const float* __restrict__ bout,
                         float* __restrict__ out){
  __shared__ float  qs[QPB][C_DIM+4];        // q staging; reused as slot sums
  __shared__ float  offs[QPB][68];           // 68 mod 32 = 4
  __shared__ float  attns[QPB][36];
  __shared__ float  logits[QPB][36];
  __shared__ float2 refs[QPB][S_CAM*D_Z+1];  // 49 f2 rows
  __shared__ int    activ[QPB][S_CAM];
  __shared__ float  cinv[QPB];

  const int tid = threadIdx.x;
  const int n0  = blockIdx.x * QPB;
  const int mflag = flag[0];
  const int qi = tid >> 5;                   // query in block (gather mapping)
  const int l  = tid & 31;                   // lane within query group
  const int wi = tid >> 6;                   // wave index (0..3)
  const int ln = tid & 63;
  const int kh = ln >> 5;                    // k-half within wave
  const int cg = ln & 31;                    // col-group within half

  // ---- 0) ref prefetch (QPB*48 = 384 float2) ----
  float2 rpre0, rpre1;
  {
    const int q0 = tid/48, r0 = tid%48;
    rpre0 = ((const float2*)ref)[((size_t)(r0>>3)*N_Q + (n0+q0))*D_Z + (r0&7)];
    if(tid < 128){
      const int e1 = tid + 256;
      const int q1 = e1/48, r1 = e1%48;
      rpre1 = ((const float2*)ref)[((size_t)(r1>>3)*N_Q + (n0+q1))*D_Z + (r1&7)];
    }
  }

  // ---- 1) q = query + query_pos ----
  {
    const float4* qa = (const float4*)(query     + (size_t)n0*C_DIM);
    const float4* qb = (const float4*)(query_pos + (size_t)n0*C_DIM);
    const int r = tid >> 5, c4 = tid & 31;
    const float4 A = qa[tid], B = qb[tid];
    *(float4*)&qs[r][c4*4] = make_float4(A.x+B.x, A.y+B.y, A.z+B.z, A.w+B.w);
  }
  __syncthreads();

  // ---- 2) projections, k-split across wave halves ----
  // cols 0..63 = Wo (offsets), cols 64..95 = Wa (logits): 24 float4 groups.
  {
    const int qA = 2*wi, qB = qA+1;
    float a0=0.f,a1=0.f,a2=0.f,a3=0.f, b0=0.f,b1=0.f,b2=0.f,b3=0.f;
    if(cg < 24){
      const float* Wp; int stride;
      if(cg < 16){ Wp = Wo + cg*4;      stride = 64; }
      else       { Wp = Wa + (cg-16)*4; stride = 32; }
      if(kh==0){
        const float4 bia = (cg<16) ? *(const float4*)&bo[cg*4]
                                   : *(const float4*)&ba[(cg-16)*4];
        a0=bia.x; a1=bia.y; a2=bia.z; a3=bia.w;
        b0=bia.x; b1=bia.y; b2=bia.z; b3=bia.w;
      }
      Wp += (size_t)kh*64*stride;
      const int k00 = kh*64;
      for(int k0=0;k0<64;k0+=4){
        const float4 qa = *(const float4*)&qs[qA][k00+k0];
        const float4 qb = *(const float4*)&qs[qB][k00+k0];
        const float4 w0 = *(const float4*)&Wp[0];
        const float4 w1 = *(const float4*)&Wp[stride];
        const float4 w2 = *(const float4*)&Wp[2*stride];
        const float4 w3 = *(const float4*)&Wp[3*stride];
        a0 += qa.x*w0.x + qa.y*w1.x + qa.z*w2.x + qa.w*w3.x;
        a1 += qa.x*w0.y + qa.y*w1.y + qa.z*w2.y + qa.w*w3.y;
        a2 += qa.x*w0.z + qa.y*w1.z + qa.z*w2.z + qa.w*w3.z;
        a3 += qa.x*w0.w + qa.y*w1.w + qa.z*w2.w + qa.w*w3.w;
        b0 += qb.x*w0.x + qb.y*w1.x + qb.z*w2.x + qb.w*w3.x;
        b1 += qb.x*w0.y + qb.y*w1.y + qb.z*w2.y + qb.w*w3.y;
        b2 += qb.x*w0.z + qb.y*w1.z + qb.z*w2.z + qb.w*w3.z;
        b3 += qb.x*w0.w + qb.y*w1.w + qb.z*w2.w + qb.w*w3.w;
        Wp += 4*stride;
      }
    }
    a0 += __shfl_xor(a0,32); a1 += __shfl_xor(a1,32);
    a2 += __shfl_xor(a2,32); a3 += __shfl_xor(a3,32);
    b0 += __shfl_xor(b0,32); b1 += __shfl_xor(b1,32);
    b2 += __shfl_xor(b2,32); b3 += __shfl_xor(b3,32);
    if(cg < 24){
      const float4 r = kh ? make_float4(b0,b1,b2,b3) : make_float4(a0,a1,a2,a3);
      const int q = qA + kh;                 // kh=0 writes qA, kh=1 writes qB
      if(cg < 16) *(float4*)&offs[q][cg*4] = r;
      else        *(float4*)&logits[q][(cg-16)*4] = r;
    }
  }
  {
    refs[tid/48][tid%48] = rpre0;
    if(tid < 128){
      const int e1 = tid + 256;
      refs[e1/48][e1%48] = rpre1;
    }
  }
  if(tid < QPB*S_CAM){
    const int q2 = tid / S_CAM, s = tid % S_CAM;
    activ[q2][s] = mask_any(mask, mflag, ((size_t)s*N_Q + (n0+q2))*D_Z) ? 1 : 0;
  }
  __syncthreads();
  if(tid < QPB*4){                           // softmax over P=8: (q2, h)
    const int q2 = tid >> 2, h = tid & 3;
    const float* L = &logits[q2][h*8];
    float mx = L[0];
    #pragma unroll
    for(int p=1;p<8;p++) mx = fmaxf(mx, L[p]);
    float e[8], ssum = 0.f;
    #pragma unroll
    for(int p=0;p<8;p++){ e[p] = __expf(L[p]-mx); ssum += e[p]; }
    const float inv = 1.f/ssum;
    #pragma unroll
    for(int p=0;p<8;p++) attns[q2][h*8+p] = e[p]*inv;
  } else if(tid >= 256-QPB){
    const int q2 = tid - (256-QPB);
    int c = 0;
    #pragma unroll
    for(int s=0;s<S_CAM;s++) c += activ[q2][s];
    cinv[q2] = 1.f / fmaxf((float)c, 1.f);
  }
  __syncthreads();

  // ---- 3) barrier-free FP8 gather: 3 cams x 4 points per lane ----
  const int pg  = l >> 4;                    // points pg*4 .. pg*4+3
  const int sg  = (l >> 3) & 1;              // cams sg*3 .. sg*3+2
  const int ll  = l & 7;                     // 16-ch group
  const int gch = ll*16;                     // first channel
  const int gh  = ll >> 1;                   // head (32 ch/head)
  f32x2 acc2[8];
  #pragma unroll
  for(int i=0;i<8;i++) acc2[i] = (f32x2){0.f, 0.f};

  for(int s=sg*3; s<sg*3+3; s++){
    if(!activ[qi][s]) continue;
    const unsigned char* vb = v8 + (size_t)s*M_VAL*C_DIM + gch;
    #pragma unroll 2
    for(int pp=0;pp<4;pp++){                 // point p <-> z-anchor d=p (P//D==1)
      const int p = pg*4 + pp;
      const float2 r2 = refs[qi][s*8+p];
      const float ox = offs[qi][gh*16+p*2+0];
      const float oy = offs[qi][gh*16+p*2+1];
      const float x = fmaf(r2.x, (float)WF, ox - 0.5f);
      const float y = fmaf(r2.y, (float)HF, oy - 0.5f);
      const float x0f = floorf(x), y0f = floorf(y);
      const float fx = x - x0f,    fy = y - y0f;
      const int x0 = (int)x0f, y0 = (int)y0f;
      const int x1 = x0+1,     y1 = y0+1;
      const float at = attns[qi][gh*8+p];
      const float wx0 = (x0>=0 && x0<WF) ? (1.f-fx) : 0.f;
      const float wx1 = (x1>=0 && x1<WF) ? fx       : 0.f;
      const float wy0 = ((y0>=0 && y0<HF) ? (1.f-fy) : 0.f) * at;
      const float wy1 = ((y1>=0 && y1<HF) ? fy       : 0.f) * at;
      const int x0c = min(max(x0,0), WF-1), x1c = min(max(x1,0), WF-1);
      const int y0c = min(max(y0,0), HF-1), y1c = min(max(y1,0), HF-1);
      const float w00 = wx0*wy0, w01 = wx1*wy0, w10 = wx0*wy1, w11 = wx1*wy1;
      const uint4 c00 = *(const uint4*)(vb + (size_t)(y0c*WF+x0c)*C_DIM);
      const uint4 c01 = *(const uint4*)(vb + (size_t)(y0c*WF+x1c)*C_DIM);
      const uint4 c10 = *(const uint4*)(vb + (size_t)(y1c*WF+x0c)*C_DIM);
      const uint4 c11 = *(const uint4*)(vb + (size_t)(y1c*WF+x1c)*C_DIM);
      corner_acc(c00, w00, acc2);
      corner_acc(c01, w01, acc2);
      corner_acc(c10, w10, acc2);
      corner_acc(c11, w11, acc2);
    }
  }

  // ---- 4) merge 4 (pg,sg) partials in-register: same-wave butterflies ----
  float* accf = (float*)acc2;
  #pragma unroll
  for(int i=0;i<16;i++) accf[i] += __shfl_xor(accf[i], 16);  // merge pt halves
  #pragma unroll
  for(int i=0;i<16;i++) accf[i] += __shfl_xor(accf[i], 8);   // merge cam halves
  if(l < 8){                                 // one copy per 16-ch group writes
    const float inv = cinv[qi];
    #pragma unroll
    for(int i=0;i<4;i++)
      *(float4*)&qs[qi][gch+i*4] = make_float4(accf[i*4+0]*inv, accf[i*4+1]*inv,
                                               accf[i*4+2]*inv, accf[i*4+3]*inv);
  }
  // qs rows 2wi/2wi+1 are written and read only by this wave; DS ops from one
  // wave complete in order -> no block barrier needed here.

  // ---- 5) out-proj + residual, k-split across wave halves ----
  {
    const int qA = 2*wi, qB = qA+1;
    const int c0 = cg*4;
    float o0=0.f,o1=0.f,o2=0.f,o3=0.f, p0=0.f,p1=0.f,p2=0.f,p3=0.f;
    if(kh==0){                               // bias+residual once
      const float4 bb = *(const float4*)&bout[c0];
      const float4 rA = *(const float4*)&query[(size_t)(n0+qA)*C_DIM + c0];
      const float4 rB = *(const float4*)&query[(size_t)(n0+qB)*C_DIM + c0];
      o0=bb.x+rA.x; o1=bb.y+rA.y; o2=bb.z+rA.z; o3=bb.w+rA.w;
      p0=bb.x+rB.x; p1=bb.y+rB.y; p2=bb.z+rB.z; p3=bb.w+rB.w;
    }
    const float* Wp = Wout + (size_t)kh*64*C_DIM + c0;
    const int k00 = kh*64;
    for(int k0=0;k0<64;k0+=4){
      const float4 sa = *(const float4*)&qs[qA][k00+k0];
      const float4 sb = *(const float4*)&qs[qB][k00+k0];
      const float4 w0 = *(const float4*)&Wp[0];
      const float4 w1 = *(const float4*)&Wp[C_DIM];
      const float4 w2 = *(const float4*)&Wp[2*C_DIM];
      const float4 w3 = *(const float4*)&Wp[3*C_DIM];
      o0 += sa.x*w0.x + sa.y*w1.x + sa.z*w2.x + sa.w*w3.x;
      o1 += sa.x*w0.y + sa.y*w1.y + sa.z*w2.y + sa.w*w3.y;
      o2 += sa.x*w0.z + sa.y*w1.z + sa.z*w2.z + sa.w*w3.z;
      o3 += sa.x*w0.w + sa.y*w1.w + sa.z*w2.w + sa.w*w3.w;
      p0 += sb.x*w0.x + sb.y*w1.x + sb.z*w2.x + sb.w*w3.x;
      p1 += sb.x*w0.y + sb.y*w1.y + sb.z*w2.y + sb.w*w3.y;
      p2 += sb.x*w0.z + sb.y*w1.z + sb.z*w2.z + sb.w*w3.z;
      p3 += sb.x*w0.w + sb.y*w1.w + sb.z*w2.w + sb.w*w3.w;
      Wp += 4*C_DIM;
    }
    o0 += __shfl_xor(o0,32); o1 += __shfl_xor(o1,32);
    o2 += __shfl_xor(o2,32); o3 += __shfl_xor(o3,32);
    p0 += __shfl_xor(p0,32); p1 += __shfl_xor(p1,32);
    p2 += __shfl_xor(p2,32); p3 += __shfl_xor(p3,32);
    const int n = n0 + qA + kh;              // kh=0 stores qA, kh=1 stores qB
    const float4 r = kh ? make_float4(p0,p1,p2,p3) : make_float4(o0,o1,o2,o3);
    *(float4*)&out[(size_t)n*C_DIM + c0] = r;
  }
}

extern "C" void kernel_launch(void* const* d_in, const int* in_sizes, int n_in,
                              void* d_out, int out_size, void* d_ws, size_t ws_size,
                              hipStream_t stream){
  const float* query     = (const float*)d_in[0];
  const float* query_pos = (const float*)d_in[1];
  const float* value     = (const float*)d_in[2];
  const float* ref       = (const float*)d_in[3];
  const unsigned char* mask = (const unsigned char*)d_in[4];
  const float* Wv   = (const float*)d_in[5];
  const float* bv   = (const float*)d_in[6];
  const float* Wo   = (const float*)d_in[7];
  const float* bo   = (const float*)d_in[8];
  const float* Wa   = (const float*)d_in[9];
  const float* ba   = (const float*)d_in[10];
  const float* Wout = (const float*)d_in[11];
  const float* bout = (const float*)d_in[12];
  float* out = (float*)d_out;

  int* flag = (int*)d_ws;
  unsigned char* v8 = (unsigned char*)((char*)d_ws + 64);

  value_proj_kernel<<<(S_CAM*M_VAL)/8, 256, 0, stream>>>(value, Wv, bv, v8, mask, flag);
  fused_deform_kernel<<<N_Q/QPB, 256, 0, stream>>>(v8, query, query_pos,
                                                   Wo, bo, Wa, ba, ref, mask, flag,
                                                   Wout, bout, out);
}